// Round 1
// baseline (1243.342 us; speedup 1.0000x reference)
//
#include <hip/hip_runtime.h>
#include <math.h>

#define BT 2048

typedef __attribute__((ext_vector_type(8))) short bf16x8;
typedef __attribute__((ext_vector_type(4))) float f32x4;

__device__ inline unsigned short f2bf(float f) {
    union { float f; unsigned u; } v; v.f = f;
    unsigned r = (v.u >> 16) & 1u;
    return (unsigned short)((v.u + 0x7FFFu + r) >> 16);
}
__device__ inline float bf2f(unsigned short s) {
    union { unsigned u; float f; } v; v.u = ((unsigned)s) << 16;
    return v.f;
}

__device__ inline float dot4(const float4 a, const float4 b) {
    return fmaf(a.x, b.x, fmaf(a.y, b.y, fmaf(a.z, b.z, a.w * b.w)));
}

union F8 { float4 v2[2]; float f[8]; };

// ---------------------------------------------------------------------------
// Pre-swizzle weights into MFMA B-fragment order, SPLIT bf16 hi/lo.
__global__ __launch_bounds__(256) void k_prep(const float* __restrict__ inW,
                                              const float* __restrict__ gatW,
                                              unsigned short* __restrict__ dst) {
    int gid = blockIdx.x * 256 + threadIdx.x;   // 0..65535
    int mat = gid >> 14;
    int r   = gid & 16383;
    int ks  = r >> 10;
    int nt  = (r >> 6) & 15;
    int lane = r & 63;
    int ln15 = lane & 15, q = lane >> 4;
    int n  = nt * 16 + ln15;
    int k0 = ks * 32 + q * 8;
    const float* src; bool tr;
    if (mat == 0) { src = inW; tr = true; }
    else          { src = gatW + (size_t)(mat - 1) * 65536; tr = false; }
    unsigned short* d = dst + ((size_t)mat * 16384 + r) * 16;
    #pragma unroll
    for (int j = 0; j < 8; j++) {
        float v = tr ? src[n * 256 + k0 + j] : src[(size_t)(k0 + j) * 256 + n];
        unsigned short hi = f2bf(v);
        d[j]     = hi;
        d[8 + j] = f2bf(v - bf2f(hi));
    }
}

// split a float8 (two float4) into hi/lo bf16x8 fragments
__device__ inline void split8(const float4 a0, const float4 a1, bf16x8& hi, bf16x8& lo) {
    union { bf16x8 v; unsigned short u[8]; } H, L;
    float f[8] = {a0.x, a0.y, a0.z, a0.w, a1.x, a1.y, a1.z, a1.w};
    #pragma unroll
    for (int j = 0; j < 8; j++) {
        H.u[j] = f2bf(f[j]);
        L.u[j] = f2bf(f[j] - bf2f(H.u[j]));
    }
    hi = H.v; lo = L.v;
}

// ---------------------------------------------------------------------------
// in_proj via split MFMA: x[bt] = (feats[bt] @ W^T + b) * mask
__global__ __launch_bounds__(256, 3) void k_inproj(const float* __restrict__ feats,
                                                   const unsigned short* __restrict__ Bsw,
                                                   const float* __restrict__ bias,
                                                   const float* __restrict__ mask,
                                                   float* __restrict__ xbuf) {
    int bt = blockIdx.x;
    size_t base = (size_t)bt * 64 * 256;
    int lane = threadIdx.x & 63, w = threadIdx.x >> 6;
    int ln15 = lane & 15, q = lane >> 4;
    int m0 = w * 16;
    f32x4 acc[16];
    #pragma unroll
    for (int nt = 0; nt < 16; nt++) acc[nt] = (f32x4){0.f, 0.f, 0.f, 0.f};
    const float* arow = feats + base + (size_t)(m0 + ln15) * 256 + q * 8;
    for (int ks = 0; ks < 8; ks++) {
        float4 a0 = *(const float4*)&arow[ks * 32];
        float4 a1 = *(const float4*)&arow[ks * 32 + 4];
        bf16x8 ahi, alo;
        split8(a0, a1, ahi, alo);
        #pragma unroll
        for (int nt = 0; nt < 16; nt++) {
            const unsigned short* fb = &Bsw[((size_t)(ks * 16 + nt) * 64 + lane) * 16];
            bf16x8 bhi = *(const bf16x8*)&fb[0];
            bf16x8 blo = *(const bf16x8*)&fb[8];
            acc[nt] = __builtin_amdgcn_mfma_f32_16x16x32_bf16(ahi, bhi, acc[nt], 0, 0, 0);
            acc[nt] = __builtin_amdgcn_mfma_f32_16x16x32_bf16(alo, bhi, acc[nt], 0, 0, 0);
            acc[nt] = __builtin_amdgcn_mfma_f32_16x16x32_bf16(ahi, blo, acc[nt], 0, 0, 0);
        }
    }
    float mk[4];
    #pragma unroll
    for (int r = 0; r < 4; r++) mk[r] = mask[bt * 64 + m0 + q * 4 + r] > 0.5f ? 1.f : 0.f;
    #pragma unroll
    for (int nt = 0; nt < 16; nt++) {
        float bv = bias[nt * 16 + ln15];
        #pragma unroll
        for (int r = 0; r < 4; r++) {
            xbuf[base + (size_t)(m0 + q * 4 + r) * 256 + nt * 16 + ln15] = (acc[nt][r] + bv) * mk[r];
        }
    }
}

// ---------------------------------------------------------------------------
// Fused GAT layer, 512 threads = 8 waves per (b,t) block.
//  A : positions/mask -> LDS; wES; A3: self-loop averages.
//  B : h = x@W split MFMA (x direct from global). Wave pair: rows chunk*16..+16,
//      n-half = w&1.
//  C : h -> hT LDS bf16 hi/lo c-major; PER-HEAD a_src/a_dst partials from regs
//      (lane channel c = half*128 + ntl*16 + ln15 -> head = half*2 + (ntl>>2)).
//  E : wave = (head, d-half): logits in MFMA A-frag layout; softmax via 2
//      shuffle rounds; alpha hi/lo A-frags in regs; P·H via MFMA.
//  F : LN over c (4 heads' partials via LDS) + relu, write x in place.
__global__ __launch_bounds__(512, 2) void k_gat(float* __restrict__ xbuf,
                                                const float* __restrict__ boxes,
                                                const float* __restrict__ maskp,
                                                const unsigned short* __restrict__ Bsw,
                                                const float* __restrict__ edgeW,
                                                const float* __restrict__ attS,
                                                const float* __restrict__ attD,
                                                const float* __restrict__ attE,
                                                const float* __restrict__ bias,
                                                const float* __restrict__ lns,
                                                const float* __restrict__ lnb) {
    int bt = blockIdx.x;
    size_t base = (size_t)bt * 64 * 256;
    __shared__ unsigned short hT[256 * 136];     // h bf16: [c][0..63]=hi, [64..127]=lo
    __shared__ float pxS[64], pyS[64], vmS[64];
    __shared__ float loopS[64 * 3];
    __shared__ float asrcS[4][64], adstS[4][64]; // PER-HEAD [h][m]
    __shared__ float wES[12];
    __shared__ float sumsS[64][8];               // [d][head*2 + {sum,sum2}]
    __shared__ float mrsS[64][2];
    int tid = threadIdx.x, lane = tid & 63, w = tid >> 6;
    int ln15 = lane & 15, q = lane >> 4;

    // Phase A: positions + wES
    if (tid < 64) {
        const float* bx = boxes + (size_t)(bt * 64 + tid) * 5;
        pxS[tid] = bx[1];
        pyS[tid] = bx[2];
        vmS[tid] = maskp[bt * 64 + tid];
    } else if (tid < 76) {
        int e = (tid - 64) >> 2, h2 = (tid - 64) & 3;
        float sm = 0.f;
        for (int c = 0; c < 64; c++)
            sm += edgeW[e * 256 + h2 * 64 + c] * attE[h2 * 64 + c];
        wES[e * 4 + h2] = sm;
    }
    __syncthreads();

    // Phase A3: self-loop edge-attr averages
    {
        int d = tid >> 3, part = tid & 7;
        float pxd = pxS[d], pyd = pyS[d];
        bool vd = vmS[d] > 0.5f;
        float deg = 0.f, s0 = 0.f, s1 = 0.f, s2 = 0.f;
        #pragma unroll
        for (int k = 0; k < 8; k++) {
            int s = part * 8 + k;
            float rx = pxd - pxS[s], ry = pyd - pyS[s];
            float dist = sqrtf(fmaxf(rx * rx + ry * ry, 1e-12f));
            bool adj = vd && (vmS[s] > 0.5f) && (dist < 0.3f) && (s != d);
            if (adj) { deg += 1.f; s0 += dist; s1 += rx; s2 += ry; }
        }
        #pragma unroll
        for (int off = 1; off < 8; off <<= 1) {
            deg += __shfl_xor(deg, off);
            s0  += __shfl_xor(s0, off);
            s1  += __shfl_xor(s1, off);
            s2  += __shfl_xor(s2, off);
        }
        if (part == 0) {
            float dg = fmaxf(deg, 1.f);
            loopS[d * 3 + 0] = s0 / dg;
            loopS[d * 3 + 1] = s1 / dg;
            loopS[d * 3 + 2] = s2 / dg;
        }
    }

    // Phase B: split MFMA h = x@W. chunk rows, n-half.
    int chunk = w >> 1, half = w & 1;
    int m0 = chunk * 16;
    f32x4 acc[8];
    #pragma unroll
    for (int ntl = 0; ntl < 8; ntl++) acc[ntl] = (f32x4){0.f, 0.f, 0.f, 0.f};
    {
        const float* arow = xbuf + base + (size_t)(m0 + ln15) * 256 + q * 8;
        for (int ks = 0; ks < 8; ks++) {
            float4 a0 = *(const float4*)&arow[ks * 32];
            float4 a1 = *(const float4*)&arow[ks * 32 + 4];
            bf16x8 ahi, alo;
            split8(a0, a1, ahi, alo);
            #pragma unroll
            for (int ntl = 0; ntl < 8; ntl++) {
                int nt = half * 8 + ntl;
                const unsigned short* fb = &Bsw[((size_t)(ks * 16 + nt) * 64 + lane) * 16];
                bf16x8 bhi = *(const bf16x8*)&fb[0];
                bf16x8 blo = *(const bf16x8*)&fb[8];
                acc[ntl] = __builtin_amdgcn_mfma_f32_16x16x32_bf16(ahi, bhi, acc[ntl], 0, 0, 0);
                acc[ntl] = __builtin_amdgcn_mfma_f32_16x16x32_bf16(alo, bhi, acc[ntl], 0, 0, 0);
                acc[ntl] = __builtin_amdgcn_mfma_f32_16x16x32_bf16(ahi, blo, acc[ntl], 0, 0, 0);
            }
        }
    }

    // Phase C: hT (bf16 hi/lo, c-major) + PER-HEAD a_src/a_dst partials.
    // Lane channel c = half*128 + ntl*16 + ln15 -> head hh2 = half*2 + (ntl>>2).
    {
        float pS_[2][4] = {{0.f,0.f,0.f,0.f},{0.f,0.f,0.f,0.f}};
        float pD_[2][4] = {{0.f,0.f,0.f,0.f},{0.f,0.f,0.f,0.f}};
        #pragma unroll
        for (int ntl = 0; ntl < 8; ntl++) {
            int c = (half * 8 + ntl) * 16 + ln15;
            int hh = ntl >> 2;   // head-within-half
            float aS = attS[c], aD = attD[c];
            #pragma unroll
            for (int r = 0; r < 4; r++) {
                float v = acc[ntl][r];
                pS_[hh][r] = fmaf(v, aS, pS_[hh][r]);
                pD_[hh][r] = fmaf(v, aD, pD_[hh][r]);
                unsigned short hi = f2bf(v);
                unsigned short lo = f2bf(v - bf2f(hi));
                int s = m0 + q * 4 + r;
                hT[(size_t)c * 136 + s] = hi;
                hT[(size_t)c * 136 + 64 + s] = lo;
            }
        }
        #pragma unroll
        for (int off = 1; off < 16; off <<= 1) {
            #pragma unroll
            for (int hh = 0; hh < 2; hh++)
                #pragma unroll
                for (int r = 0; r < 4; r++) {
                    pS_[hh][r] += __shfl_xor(pS_[hh][r], off);
                    pD_[hh][r] += __shfl_xor(pD_[hh][r], off);
                }
        }
        if (ln15 == 0) {
            #pragma unroll
            for (int hh = 0; hh < 2; hh++)
                #pragma unroll
                for (int r = 0; r < 4; r++) {
                    asrcS[half * 2 + hh][m0 + q * 4 + r] = pS_[hh][r];
                    adstS[half * 2 + hh][m0 + q * 4 + r] = pD_[hh][r];
                }
        }
    }
    __syncthreads();

    // Phase E: logits in A-frag layout, softmax, alpha hi/lo frags, P·H MFMA.
    int head = w >> 1;
    int base_d = (w & 1) * 32;
    f32x4 macc[2][4];
    #pragma unroll
    for (int t = 0; t < 2; t++)
        #pragma unroll
        for (int ct = 0; ct < 4; ct++) macc[t][ct] = (f32x4){0.f, 0.f, 0.f, 0.f};
    {
        float pxd[2], pyd[2], adstv[2], lp0[2], lp1[2], lp2[2];
        int dcur[2];
        bool vdv[2];
        #pragma unroll
        for (int t = 0; t < 2; t++) {
            int d = base_d + t * 16 + ln15;
            dcur[t] = d;
            pxd[t] = pxS[d]; pyd[t] = pyS[d];
            vdv[t] = vmS[d] > 0.5f;
            adstv[t] = adstS[head][d];
            lp0[t] = loopS[d * 3 + 0];
            lp1[t] = loopS[d * 3 + 1];
            lp2[t] = loopS[d * 3 + 2];
        }
        float we0 = wES[head], we1 = wES[4 + head], we2 = wES[8 + head];

        float lg[2][16];
        #pragma unroll
        for (int ks = 0; ks < 2; ks++) {
            int s0 = ks * 32 + q * 8;
            F8 PX, PY, VM, AS;
            PX.v2[0] = *(const float4*)&pxS[s0]; PX.v2[1] = *(const float4*)&pxS[s0 + 4];
            PY.v2[0] = *(const float4*)&pyS[s0]; PY.v2[1] = *(const float4*)&pyS[s0 + 4];
            VM.v2[0] = *(const float4*)&vmS[s0]; VM.v2[1] = *(const float4*)&vmS[s0 + 4];
            AS.v2[0] = *(const float4*)&asrcS[head][s0];
            AS.v2[1] = *(const float4*)&asrcS[head][s0 + 4];
            #pragma unroll
            for (int j = 0; j < 8; j++) {
                int s = s0 + j;
                float vsf = VM.f[j];
                #pragma unroll
                for (int t = 0; t < 2; t++) {
                    float rx = pxd[t] - PX.f[j], ry = pyd[t] - PY.f[j];
                    float dist = sqrtf(fmaxf(rx * rx + ry * ry, 1e-12f));
                    bool self = (s == dcur[t]);
                    bool adj = vdv[t] && (vsf > 0.5f) && (dist < 0.3f) && !self;
                    float e0 = adj ? dist : (self ? lp0[t] : 0.f);
                    float e1 = adj ? rx   : (self ? lp1[t] : 0.f);
                    float e2 = adj ? ry   : (self ? lp2[t] : 0.f);
                    bool fa = adj || (self && vdv[t]);
                    float l = AS.f[j] + adstv[t] + e0 * we0 + e1 * we1 + e2 * we2;
                    l = l >= 0.f ? l : 0.2f * l;
                    lg[t][ks * 8 + j] = fa ? l : -1e9f;
                }
            }
        }

        // softmax over s (in-lane 16 + xor16/xor32 over q) + alpha frags
        bf16x8 ah[2][2], al[2][2];
        #pragma unroll
        for (int t = 0; t < 2; t++) {
            float mx = lg[t][0];
            #pragma unroll
            for (int j = 1; j < 16; j++) mx = fmaxf(mx, lg[t][j]);
            mx = fmaxf(mx, __shfl_xor(mx, 16));
            mx = fmaxf(mx, __shfl_xor(mx, 32));
            float ee[16], sm = 0.f;
            #pragma unroll
            for (int j = 0; j < 16; j++) { ee[j] = __expf(lg[t][j] - mx); sm += ee[j]; }
            sm += __shfl_xor(sm, 16);
            sm += __shfl_xor(sm, 32);
            float inv = 1.f / sm;
            #pragma unroll
            for (int ks2 = 0; ks2 < 2; ks2++) {
                union { bf16x8 v; unsigned short u[8]; } H, L;
                #pragma unroll
                for (int j = 0; j < 8; j++) {
                    float a = ee[ks2 * 8 + j] * inv;
                    unsigned short hi = f2bf(a);
                    H.u[j] = hi;
                    L.u[j] = f2bf(a - bf2f(hi));
                }
                ah[t][ks2] = H.v; al[t][ks2] = L.v;
            }
        }

        // P·H MFMA: msg[d][c] for d in base_d..+32, c in head*64..+64
        #pragma unroll
        for (int t = 0; t < 2; t++) {
            #pragma unroll
            for (int ks2 = 0; ks2 < 2; ks2++) {
                #pragma unroll
                for (int ct = 0; ct < 4; ct++) {
                    const unsigned short* hb =
                        &hT[(size_t)(head * 64 + ct * 16 + ln15) * 136 + ks2 * 32 + q * 8];
                    bf16x8 bhi = *(const bf16x8*)&hb[0];
                    bf16x8 blo = *(const bf16x8*)&hb[64];
                    macc[t][ct] = __builtin_amdgcn_mfma_f32_16x16x32_bf16(ah[t][ks2], bhi, macc[t][ct], 0, 0, 0);
                    macc[t][ct] = __builtin_amdgcn_mfma_f32_16x16x32_bf16(al[t][ks2], bhi, macc[t][ct], 0, 0, 0);
                    macc[t][ct] = __builtin_amdgcn_mfma_f32_16x16x32_bf16(ah[t][ks2], blo, macc[t][ct], 0, 0, 0);
                }
            }
        }
    }

    // Phase F: LN(msg + bias + x_old) + relu. Each wave owns (head c-range, d-half).
    {
        float bsv[4], scv[4], bbv[4];
        #pragma unroll
        for (int ct = 0; ct < 4; ct++) {
            int c = head * 64 + ct * 16 + ln15;
            bsv[ct] = bias[c];
            scv[ct] = lns[c];
            bbv[ct] = lnb[c];
        }
        float xo[2][4][4];
        #pragma unroll
        for (int t = 0; t < 2; t++)
            #pragma unroll
            for (int r = 0; r < 4; r++) {
                int d = base_d + t * 16 + q * 4 + r;
                #pragma unroll
                for (int ct = 0; ct < 4; ct++)
                    xo[t][ct][r] = xbuf[base + (size_t)d * 256 + head * 64 + ct * 16 + ln15];
            }
        float ps[8], ps2[8];
        #pragma unroll
        for (int t = 0; t < 2; t++)
            #pragma unroll
            for (int r = 0; r < 4; r++) {
                float s = 0.f, s2 = 0.f;
                #pragma unroll
                for (int ct = 0; ct < 4; ct++) {
                    float v = macc[t][ct][r] + xo[t][ct][r] + bsv[ct];
                    s += v; s2 += v * v;
                }
                ps[t * 4 + r] = s; ps2[t * 4 + r] = s2;
            }
        #pragma unroll
        for (int off = 1; off < 16; off <<= 1) {
            #pragma unroll
            for (int i = 0; i < 8; i++) {
                ps[i]  += __shfl_xor(ps[i], off);
                ps2[i] += __shfl_xor(ps2[i], off);
            }
        }
        if (ln15 == 0) {
            #pragma unroll
            for (int t = 0; t < 2; t++)
                #pragma unroll
                for (int r = 0; r < 4; r++) {
                    int d = base_d + t * 16 + q * 4 + r;
                    sumsS[d][head * 2 + 0] = ps[t * 4 + r];
                    sumsS[d][head * 2 + 1] = ps2[t * 4 + r];
                }
        }
        __syncthreads();
        if (tid < 64) {
            float S  = sumsS[tid][0] + sumsS[tid][2] + sumsS[tid][4] + sumsS[tid][6];
            float S2 = sumsS[tid][1] + sumsS[tid][3] + sumsS[tid][5] + sumsS[tid][7];
            float mu = S * (1.f / 256.f);
            float var = S2 * (1.f / 256.f) - mu * mu;
            mrsS[tid][0] = mu;
            mrsS[tid][1] = rsqrtf(var + 1e-5f);
        }
        __syncthreads();
        #pragma unroll
        for (int t = 0; t < 2; t++)
            #pragma unroll
            for (int r = 0; r < 4; r++) {
                int d = base_d + t * 16 + q * 4 + r;
                float mu = mrsS[d][0], rs = mrsS[d][1];
                #pragma unroll
                for (int ct = 0; ct < 4; ct++) {
                    float v = (macc[t][ct][r] + xo[t][ct][r] + bsv[ct] - mu) * rs * scv[ct] + bbv[ct];
                    xbuf[base + (size_t)d * 256 + head * 64 + ct * 16 + ln15] = fmaxf(v, 0.f);
                }
            }
    }
}

// ---------------------------------------------------------------------------
// frame + temp proj, 4 tokens per block (weight reuse + ILP)
__global__ __launch_bounds__(256) void k_frame_temp4(const float* __restrict__ xbuf,
                                                     const float* __restrict__ mask,
                                                     const float* __restrict__ tW,
                                                     const float* __restrict__ tb,
                                                     const float* __restrict__ pe,
                                                     float* __restrict__ ybuf) {
    int b4 = blockIdx.x;   // 0..511
    int tid = threadIdx.x;
    __shared__ float frS[4][256];
    __shared__ float nvS[4];
    if (tid < 4) {
        int bt = b4 * 4 + tid;
        float nv = 0.f;
        for (int m = 0; m < 64; m++) nv += (mask[bt * 64 + m] > 0.5f) ? 1.f : 0.f;
        nvS[tid] = fmaxf(nv, 1.f);
    }
    float fr[4] = {0.f, 0.f, 0.f, 0.f};
    for (int m = 0; m < 64; m++) {
        #pragma unroll
        for (int t = 0; t < 4; t++) {
            int bt = b4 * 4 + t;
            float vmv = mask[bt * 64 + m] > 0.5f ? 1.f : 0.f;
            fr[t] += xbuf[((size_t)bt * 64 + m) * 256 + tid] * vmv;
        }
    }
    __syncthreads();
    #pragma unroll
    for (int t = 0; t < 4; t++) frS[t][tid] = fr[t] / nvS[t];
    __syncthreads();
    float acc[4];
    #pragma unroll
    for (int t = 0; t < 4; t++) acc[t] = tb[tid] + pe[((b4 * 4 + t) & 31) * 256 + tid];
    const float* wrow = tW + (size_t)tid * 256;
    for (int g = 0; g < 256; g += 4) {
        float4 wv = *(const float4*)&wrow[g];
        #pragma unroll
        for (int t = 0; t < 4; t++) acc[t] += dot4(*(const float4*)&frS[t][g], wv);
    }
    #pragma unroll
    for (int t = 0; t < 4; t++) ybuf[(size_t)(b4 * 4 + t) * 256 + tid] = acc[t];
}

// ---------------------------------------------------------------------------
// LN1 + qkv, 4 tokens per block; wave-per-token LN.
__global__ __launch_bounds__(256) void k_ln_qkv4(const float* __restrict__ ybuf,
                                                 const float* __restrict__ ln_s,
                                                 const float* __restrict__ ln_b,
                                                 const float* __restrict__ qW,
                                                 const float* __restrict__ qb,
                                                 float* __restrict__ qkvbuf) {
    int b4 = blockIdx.x, tid = threadIdx.x;
    int lane = tid & 63, wv = tid >> 6;
    __shared__ float zS[4][256];
    {
        int bt = b4 * 4 + wv;
        float4 yv = *(const float4*)&ybuf[(size_t)bt * 256 + lane * 4];
        float s = yv.x + yv.y + yv.z + yv.w;
        float s2 = yv.x * yv.x + yv.y * yv.y + yv.z * yv.z + yv.w * yv.w;
        #pragma unroll
        for (int off = 1; off < 64; off <<= 1) { s += __shfl_xor(s, off); s2 += __shfl_xor(s2, off); }
        float mu = s * (1.f / 256.f);
        float var = s2 * (1.f / 256.f) - mu * mu;
        float rstd = rsqrtf(var + 1e-5f);
        float4 ls = *(const float4*)&ln_s[lane * 4];
        float4 lb = *(const float4*)&ln_b[lane * 4];
        float4 z;
        z.x = (yv.x - mu) * rstd * ls.x + lb.x;
        z.y = (yv.y - mu) * rstd * ls.y + lb.y;
        z.z = (yv.z - mu) * rstd * ls.z + lb.z;
        z.w = (yv.w - mu) * rstd * ls.w + lb.w;
        *(float4*)&zS[wv][lane * 4] = z;
    }
    __syncthreads();
    for (int r = 0; r < 3; r++) {
        int j = r * 256 + tid;
        float acc[4];
        float bv = qb[j];
        #pragma unroll
        for (int t = 0; t < 4; t++) acc[t] = bv;
        const float* wrow = qW + (size_t)j * 256;
        for (int i = 0; i < 256; i += 4) {
            float4 wv4 = *(const float4*)&wrow[i];
            #pragma unroll
            for (int t = 0; t < 4; t++) acc[t] += dot4(*(const float4*)&zS[t][i], wv4);
        }
        #pragma unroll
        for (int t = 0; t < 4; t++) qkvbuf[(size_t)(b4 * 4 + t) * 768 + j] = acc[t];
    }
}

// ---------------------------------------------------------------------------
__global__ __launch_bounds__(64) void k_attn(const float* __restrict__ qkvbuf,
                                             float* __restrict__ obuf) {
    int blk = blockIdx.x;
    int b = blk >> 3, h = blk & 7;
    int tid = threadIdx.x;
    __shared__ float Ks[32 * 32], Vs[32 * 32];
    for (int idx = tid; idx < 1024; idx += 64) {
        int tk = idx >> 5, c = idx & 31;
        size_t qbase = ((size_t)(b * 32 + tk)) * 768 + h * 32 + c;
        Ks[idx] = qkvbuf[qbase + 256];
        Vs[idx] = qkvbuf[qbase + 512];
    }
    __syncthreads();
    if (tid < 32) {
        int tq = tid;
        float qv[32];
        size_t qb0 = ((size_t)(b * 32 + tq)) * 768 + h * 32;
        #pragma unroll
        for (int c = 0; c < 32; c++) qv[c] = qkvbuf[qb0 + c];
        float scr[32];
        float mx = -1e30f;
        #pragma unroll
        for (int tk = 0; tk < 32; tk++) {
            float dd = 0.f;
            #pragma unroll
            for (int c = 0; c < 32; c++) dd = fmaf(qv[c], Ks[tk * 32 + c], dd);
            dd *= 0.17677669529663687f;
            scr[tk] = dd;
            mx = fmaxf(mx, dd);
        }
        float sm = 0.f;
        #pragma unroll
        for (int tk = 0; tk < 32; tk++) { scr[tk] = __expf(scr[tk] - mx); sm += scr[tk]; }
        float inv = 1.f / sm;
        float o[32];
        #pragma unroll
        for (int c = 0; c < 32; c++) o[c] = 0.f;
        #pragma unroll
        for (int tk = 0; tk < 32; tk++) {
            float a = scr[tk] * inv;
            #pragma unroll
            for (int c = 0; c < 32; c++) o[c] = fmaf(a, Vs[tk * 32 + c], o[c]);
        }
        size_t ob = ((size_t)(b * 32 + tq)) * 256 + h * 32;
        #pragma unroll
        for (int c = 0; c < 32; c++) obuf[ob + c] = o[c];
    }
}

// ---------------------------------------------------------------------------
__global__ __launch_bounds__(256) void k_attn_out4(const float* __restrict__ obuf,
                                                   const float* __restrict__ W,
                                                   const float* __restrict__ bvec,
                                                   float* __restrict__ ybuf) {
    int b4 = blockIdx.x, tid = threadIdx.x;
    int lane = tid & 63, wv = tid >> 6;
    __shared__ float oS[4][256];
    *(float4*)&oS[wv][lane * 4] = *(const float4*)&obuf[(size_t)(b4 * 4 + wv) * 256 + lane * 4];
    __syncthreads();
    float acc[4];
    float bv = bvec[tid];
    #pragma unroll
    for (int t = 0; t < 4; t++) acc[t] = bv;
    const float* wrow = W + (size_t)tid * 256;
    for (int i = 0; i < 256; i += 4) {
        float4 wv4 = *(const float4*)&wrow[i];
        #pragma unroll
        for (int t = 0; t < 4; t++) acc[t] += dot4(*(const float4*)&oS[t][i], wv4);
    }
    #pragma unroll
    for (int t = 0; t < 4; t++) ybuf[(size_t)(b4 * 4 + t) * 256 + tid] += acc[t];
}

// ---------------------------------------------------------------------------
__global__ __launch_bounds__(256) void k_ff4(float* __restrict__ ybuf,
                                             const float* __restrict__ ln_s,
                                             const float* __restrict__ ln_b,
                                             const float* __restrict__ W1,
                                             const float* __restrict__ b1,
                                             const float* __restrict__ W2,
                                             const float* __restrict__ b2) {
    int b4 = blockIdx.x, tid = threadIdx.x;
    int lane = tid & 63, wv = tid >> 6;
    __shared__ float zS[4][256];
    __shared__ float fS[4][512];
    {
        int bt = b4 * 4 + wv;
        float4 yv = *(const float4*)&ybuf[(size_t)bt * 256 + lane * 4];
        float s = yv.x + yv.y + yv.z + yv.w;
        float s2 = yv.x * yv.x + yv.y * yv.y + yv.z * yv.z + yv.w * yv.w;
        #pragma unroll
        for (int off = 1; off < 64; off <<= 1) { s += __shfl_xor(s, off); s2 += __shfl_xor(s2, off); }
        float mu = s * (1.f / 256.f);
        float var = s2 * (1.f / 256.f) - mu * mu;
        float rstd = rsqrtf(var + 1e-5f);
        float4 ls = *(const float4*)&ln_s[lane * 4];
        float4 lb = *(const float4*)&ln_b[lane * 4];
        float4 z;
        z.x = (yv.x - mu) * rstd * ls.x + lb.x;
        z.y = (yv.y - mu) * rstd * ls.y + lb.y;
        z.z = (yv.z - mu) * rstd * ls.z + lb.z;
        z.w = (yv.w - mu) * rstd * ls.w + lb.w;
        *(float4*)&zS[wv][lane * 4] = z;
    }
    __syncthreads();
    for (int r = 0; r < 2; r++) {
        int j = r * 256 + tid;
        float acc[4];
        float bv = b1[j];
        #pragma unroll
        for (int t = 0; t < 4; t++) acc[t] = bv;
        const float* wrow = W1 + (size_t)j * 256;
        for (int i = 0; i < 256; i += 4) {
            float4 wv4 = *(const float4*)&wrow[i];
            #pragma unroll
            for (int t = 0; t < 4; t++) acc[t] += dot4(*(const float4*)&zS[t][i], wv4);
        }
        #pragma unroll
        for (int t = 0; t < 4; t++) fS[t][j] = fmaxf(acc[t], 0.f);
    }
    __syncthreads();
    float acc[4];
    float bv = b2[tid];
    #pragma unroll
    for (int t = 0; t < 4; t++) acc[t] = bv;
    const float* wrow = W2 + (size_t)tid * 512;
    for (int jj = 0; jj < 512; jj += 4) {
        float4 wv4 = *(const float4*)&wrow[jj];
        #pragma unroll
        for (int t = 0; t < 4; t++) acc[t] += dot4(*(const float4*)&fS[t][jj], wv4);
    }
    #pragma unroll
    for (int t = 0; t < 4; t++) {
        size_t idx = (size_t)(b4 * 4 + t) * 256 + tid;
        ybuf[idx] = ybuf[idx] + acc[t];
    }
}

// ---------------------------------------------------------------------------
__global__ __launch_bounds__(256) void k_pool_out(const float* __restrict__ ybuf,
                                                  const float* __restrict__ pW,
                                                  const float* __restrict__ pb,
                                                  const float* __restrict__ oW,
                                                  const float* __restrict__ ob,
                                                  const float* __restrict__ lns,
                                                  const float* __restrict__ lnb,
                                                  float* __restrict__ dout) {
    int b = blockIdx.x, tid = threadIdx.x;
    __shared__ float redP[256];
    __shared__ float wS[32];
    __shared__ float pS[256];
    __shared__ float red[8];
    int tq = tid >> 3, part = tid & 7;
    float partial = 0.f;
    {
        const float* yrow = ybuf + ((size_t)(b * 32 + tq)) * 256 + part * 32;
        const float* pwp = pW + part * 32;
        #pragma unroll
        for (int j = 0; j < 32; j += 4) {
            float4 yv = *(const float4*)&yrow[j];
            float4 wv = *(const float4*)&pwp[j];
            partial += dot4(yv, wv);
        }
    }
    redP[tid] = partial;
    __syncthreads();
    if (tid < 32) {
        float s = pb[0];
        for (int p = 0; p < 8; p++) s += redP[tid * 8 + p];
        float mx = s;
        #pragma unroll
        for (int off = 16; off; off >>= 1) mx = fmaxf(mx, __shfl_xor(mx, off));
        float e = __expf(s - mx);
        float sm = e;
        #pragma unroll
        for (int off = 16; off; off >>= 1) sm += __shfl_xor(sm, off);
        wS[tid] = e / sm;
    }
    __syncthreads();
    float p = 0.f;
    for (int t = 0; t < 32; t++) p += ybuf[((size_t)(b * 32 + t)) * 256 + tid] * wS[t];
    pS[tid] = p;
    __syncthreads();
    float accs[2];
    for (int r = 0; r < 2; r++) {
        int j = r * 256 + tid;
        float acc = ob[j];
        const float* wrow = oW + (size_t)j * 256;
        for (int g = 0; g < 256; g += 4) {
            float4 pv = *(const float4*)&pS[g];
            float4 wv = *(const float4*)&wrow[g];
            acc += dot4(pv, wv);
        }
        accs[r] = acc;
    }
    float s = accs[0] + accs[1];
    float s2 = accs[0] * accs[0] + accs[1] * accs[1];
    #pragma unroll
    for (int off = 32; off; off >>= 1) {
        s += __shfl_xor(s, off);
        s2 += __shfl_xor(s2, off);
    }
    int wid = threadIdx.x >> 6;
    int lane = threadIdx.x & 63;
    if (lane == 0) { red[wid] = s; red[4 + wid] = s2; }
    __syncthreads();
    s = red[0] + red[1] + red[2] + red[3];
    s2 = red[4] + red[5] + red[6] + red[7];
    float mu = s * (1.f / 512.f);
    float var = s2 * (1.f / 512.f) - mu * mu;
    float rstd = rsqrtf(var + 1e-5f);
    dout[b * 512 + tid]       = fmaxf((accs[0] - mu) * rstd * lns[tid] + lnb[tid], 0.f);
    dout[b * 512 + tid + 256] = fmaxf((accs[1] - mu) * rstd * lns[tid + 256], 0.f) * 0.f + fmaxf((accs[1] - mu) * rstd * lns[tid + 256] + lnb[tid + 256], 0.f);
}

// ---------------------------------------------------------------------------
extern "C" void kernel_launch(void* const* d_in, const int* in_sizes, int n_in,
                              void* d_out, int out_size, void* d_ws, size_t ws_size,
                              hipStream_t stream) {
    const float* drone_feats = (const float*)d_in[0];
    const float* boxes       = (const float*)d_in[1];
    const float* drone_mask  = (const float*)d_in[2];
    const float* in_proj_W   = (const float*)d_in[3];
    const float* in_proj_b   = (const float*)d_in[4];
    const float* gat_lin_W   = (const float*)d_in[5];
    const float* gat_edge_W  = (const float*)d_in[6];
    const float* gat_att_src = (const float*)d_in[7];
    const float* gat_att_dst = (const float*)d_in[8];
    const float* gat_att_edge= (const float*)d_in[9];
    const float* gat_bias    = (const float*)d_in[10];
    const float* gat_ln_s    = (const float*)d_in[11];
    const float* gat_ln_b    = (const float*)d_in[12];
    const float* temp_W      = (const float*)d_in[13];
    const float* temp_b      = (const float*)d_in[14];
    const float* pos_emb     = (const float*)d_in[15];
    const float* qkv_W       = (const float*)d_in[16];
    const float* qkv_b       = (const float*)d_in[17];
    const float* attn_out_W  = (const float*)d_in[18];
    const float* attn_out_b  = (const float*)d_in[19];
    const float* ln1_s       = (const float*)d_in[20];
    const float* ln1_b       = (const float*)d_in[21];
    const float* ln2_s       = (const float*)d_in[22];
    const float* ln2_b       = (const float*)d_in[23];
    const float* ff1_W       = (const float*)d_in[24];
    const float* ff1_b       = (const float*)d_in[25];
    const float* ff2_W       = (const float*)d_in[26];
    const float* ff2_b       = (const float*)d_in[27];
    const float* pool_W      = (const float*)d_in[28];
    const float* pool_b      = (const float*)d_in[29];
    const float* out_W       = (const float*)d_in[30];
    const float* out_b       = (const float*)d_in[31];
    const float* out_ln_s    = (const float*)d_in[32];
    const float* out_ln_b    = (const float*)d_in[33];
    float* out = (float*)d_out;

    float* ws = (float*)d_ws;
    float* xbuf = ws;
    size_t off = (size_t)BT * 64 * 256;
    unsigned short* Bsw = (unsigned short*)(ws + off); off += 4 * 16384 * 16 / 2;
    float* ybuf   = ws + off; off += (size_t)BT * 256;
    float* qkvbuf = ws + off; off += (size_t)BT * 768;
    float* obuf   = ws + off; off += (size_t)BT * 256;

    k_prep<<<dim3(256), dim3(256), 0, stream>>>(in_proj_W, gat_lin_W, Bsw);
    k_inproj<<<dim3(BT), dim3(256), 0, stream>>>(drone_feats, Bsw, in_proj_b, drone_mask, xbuf);
    for (int l = 0; l < 3; l++) {
        k_gat<<<dim3(BT), dim3(512), 0, stream>>>(xbuf, boxes, drone_mask,
            Bsw + (size_t)(1 + l) * 16384 * 16, gat_edge_W + (size_t)l * 768,
            gat_att_src + (size_t)l * 256, gat_att_dst + (size_t)l * 256,
            gat_att_edge + (size_t)l * 256, gat_bias + (size_t)l * 256,
            gat_ln_s + (size_t)l * 256, gat_ln_b + (size_t)l * 256);
    }
    k_frame_temp4<<<dim3(BT / 4), dim3(256), 0, stream>>>(xbuf, drone_mask, temp_W, temp_b, pos_emb, ybuf);
    for (int l = 0; l < 2; l++) {
        k_ln_qkv4<<<dim3(BT / 4), dim3(256), 0, stream>>>(ybuf, ln1_s + l * 256, ln1_b + l * 256,
            qkv_W + (size_t)l * 768 * 256, qkv_b + l * 768, qkvbuf);
        k_attn<<<dim3(512), dim3(64), 0, stream>>>(qkvbuf, obuf);
        k_attn_out4<<<dim3(BT / 4), dim3(256), 0, stream>>>(obuf,
            attn_out_W + (size_t)l * 65536, attn_out_b + l * 256, ybuf);
        k_ff4<<<dim3(BT / 4), dim3(256), 0, stream>>>(ybuf, ln2_s + l * 256, ln2_b + l * 256,
            ff1_W + (size_t)l * 131072, ff1_b + l * 512,
            ff2_W + (size_t)l * 131072, ff2_b + l * 256);
    }
    k_pool_out<<<dim3(64), dim3(256), 0, stream>>>(ybuf, pool_W, pool_b, out_W, out_b,
                                                   out_ln_s, out_ln_b, out);
}

// Round 2
// 1135.847 us; speedup vs baseline: 1.0946x; 1.0946x over previous
//
#include <hip/hip_runtime.h>
#include <math.h>

#define BT 2048

typedef __attribute__((ext_vector_type(8))) short bf16x8;
typedef __attribute__((ext_vector_type(4))) float f32x4;
typedef __attribute__((ext_vector_type(4))) unsigned short u16x4;

__device__ inline unsigned short f2bf(float f) {
    union { float f; unsigned u; } v; v.f = f;
    unsigned r = (v.u >> 16) & 1u;
    return (unsigned short)((v.u + 0x7FFFu + r) >> 16);
}
__device__ inline float bf2f(unsigned short s) {
    union { unsigned u; float f; } v; v.u = ((unsigned)s) << 16;
    return v.f;
}

__device__ inline float dot4(const float4 a, const float4 b) {
    return fmaf(a.x, b.x, fmaf(a.y, b.y, fmaf(a.z, b.z, a.w * b.w)));
}

union F8 { float4 v2[2]; float f[8]; };

// x/feats LDS planes: [64 rows][264 cols] ushort (pad 8 cols kills stride-256 conflicts)
#define XP 264

// ---------------------------------------------------------------------------
// Pre-swizzle weights into MFMA B-fragment order, SPLIT bf16 hi/lo.
// Only rows with ks<8 are consumed; guard the OOB tail (was reading past src).
__global__ __launch_bounds__(256) void k_prep(const float* __restrict__ inW,
                                              const float* __restrict__ gatW,
                                              unsigned short* __restrict__ dst) {
    int gid = blockIdx.x * 256 + threadIdx.x;   // 0..65535
    int mat = gid >> 14;
    int r   = gid & 16383;
    int ks  = r >> 10;
    int nt  = (r >> 6) & 15;
    int lane = r & 63;
    int ln15 = lane & 15, q = lane >> 4;
    int n  = nt * 16 + ln15;
    int k0 = ks * 32 + q * 8;
    const float* src; bool tr;
    if (mat == 0) { src = inW; tr = true; }
    else          { src = gatW + (size_t)(mat - 1) * 65536; tr = false; }
    unsigned short* d = dst + ((size_t)mat * 16384 + r) * 16;
    if (ks < 8) {
        #pragma unroll
        for (int j = 0; j < 8; j++) {
            float v = tr ? src[n * 256 + k0 + j] : src[(size_t)(k0 + j) * 256 + n];
            unsigned short hi = f2bf(v);
            d[j]     = hi;
            d[8 + j] = f2bf(v - bf2f(hi));
        }
    } else {
        #pragma unroll
        for (int j = 0; j < 8; j++) { d[j] = 0; d[8 + j] = 0; }
    }
}

// ---------------------------------------------------------------------------
// Fully fused GNN: in_proj + 3 GAT layers + masked frame mean.
// One block per (b,t); x stays resident in LDS as bf16 hi/lo planes.
// Matmul decomposition: wave w owns nt pair {2w,2w+1} (32 output channels,
// all of head w>>1) and iterates 4 m-tiles -> no cross-wave B-fragment
// duplication, and no float->bf16 splits inside the MFMA loops.
__global__ __launch_bounds__(512, 2) void k_gnn(const float* __restrict__ feats,
                                                const float* __restrict__ boxes,
                                                const float* __restrict__ maskp,
                                                const unsigned short* __restrict__ BswAll,
                                                const float* __restrict__ inb,
                                                const float* __restrict__ edgeW,
                                                const float* __restrict__ attSg,
                                                const float* __restrict__ attDg,
                                                const float* __restrict__ attEg,
                                                const float* __restrict__ gbias,
                                                const float* __restrict__ glns,
                                                const float* __restrict__ glnb,
                                                float* __restrict__ framebuf) {
    int bt = blockIdx.x;
    size_t fbase = (size_t)bt * 64 * 256;

    __shared__ unsigned short xH[64 * XP];       // x hi plane
    __shared__ unsigned short xL[64 * XP];       // x lo plane
    __shared__ unsigned short hT[256 * 136];     // h bf16 c-major (hi 0..63, lo 64..127); aliased for feats staging
    __shared__ float pxS[64], pyS[64], vmS[64];
    __shared__ float loopS[192];
    __shared__ float asrcS[8][64], adstS[8][64]; // per-WAVE partials (2 waves per head)
    __shared__ float wESall[36];                 // [l][e][h]
    __shared__ float sumsS[64][8];
    __shared__ float mrsS[64][2];
    __shared__ float nvS;

    int tid = threadIdx.x, lane = tid & 63, w = tid >> 6;
    int ln15 = lane & 15, q = lane >> 4;
    int nt0 = w * 2;
    int head = w >> 1;
    int base_d = (w & 1) * 32;

    unsigned short* fH = hT;                 // feats hi plane (staging alias)
    unsigned short* fL = hT + 64 * XP;       // feats lo plane

    // ---- Phase 0a: geometry + per-layer wES + feats staging (pre-split) ----
    if (tid < 64) {
        const float* bx = boxes + (size_t)(bt * 64 + tid) * 5;
        pxS[tid] = bx[1];
        pyS[tid] = bx[2];
        vmS[tid] = maskp[bt * 64 + tid];
    } else if (tid < 100) {
        int idx = tid - 64;                  // l*12 + e*4 + h2
        int l = idx / 12, r2 = idx - l * 12;
        int e = r2 >> 2, h2 = r2 & 3;
        float sm = 0.f;
        const float* ew = edgeW + (size_t)l * 768 + e * 256 + h2 * 64;
        const float* ae = attEg + (size_t)l * 256 + h2 * 64;
        for (int c = 0; c < 64; c++) sm += ew[c] * ae[c];
        wESall[idx] = sm;
    }
    #pragma unroll
    for (int j = 0; j < 8; j++) {
        int g = j * 2048 + tid * 4;
        int row = g >> 8, col = g & 255;
        float4 v4 = *(const float4*)&feats[fbase + g];
        union { u16x4 v; unsigned short u[4]; } H4, L4;
        float vf[4] = {v4.x, v4.y, v4.z, v4.w};
        #pragma unroll
        for (int jj = 0; jj < 4; jj++) {
            H4.u[jj] = f2bf(vf[jj]);
            L4.u[jj] = f2bf(vf[jj] - bf2f(H4.u[jj]));
        }
        *(u16x4*)&fH[row * XP + col] = H4.v;
        *(u16x4*)&fL[row * XP + col] = L4.v;
    }
    __syncthreads();

    // ---- Phase 0b: self-loop edge-attr averages + nvalid ----
    {
        int d = tid >> 3, part = tid & 7;
        float pxd = pxS[d], pyd = pyS[d];
        bool vd = vmS[d] > 0.5f;
        float deg = 0.f, s0 = 0.f, s1 = 0.f, s2 = 0.f;
        #pragma unroll
        for (int k = 0; k < 8; k++) {
            int s = part * 8 + k;
            float rx = pxd - pxS[s], ry = pyd - pyS[s];
            float dist = sqrtf(fmaxf(rx * rx + ry * ry, 1e-12f));
            bool adj = vd && (vmS[s] > 0.5f) && (dist < 0.3f) && (s != d);
            if (adj) { deg += 1.f; s0 += dist; s1 += rx; s2 += ry; }
        }
        #pragma unroll
        for (int off = 1; off < 8; off <<= 1) {
            deg += __shfl_xor(deg, off);
            s0  += __shfl_xor(s0, off);
            s1  += __shfl_xor(s1, off);
            s2  += __shfl_xor(s2, off);
        }
        if (part == 0) {
            float dg = fmaxf(deg, 1.f);
            loopS[d * 3 + 0] = s0 / dg;
            loopS[d * 3 + 1] = s1 / dg;
            loopS[d * 3 + 2] = s2 / dg;
        }
    }
    if (tid == 0) {
        float nv = 0.f;
        for (int m = 0; m < 64; m++) nv += vmS[m] > 0.5f ? 1.f : 0.f;
        nvS = fmaxf(nv, 1.f);
    }

    // ---- Phase 0c: in_proj MFMA (A from fH/fL, B = Bsw mat 0) -> xH/xL ----
    {
        f32x4 acc[4][2];
        #pragma unroll
        for (int mt = 0; mt < 4; mt++)
            #pragma unroll
            for (int ntl = 0; ntl < 2; ntl++) acc[mt][ntl] = (f32x4){0.f, 0.f, 0.f, 0.f};
        for (int ks = 0; ks < 8; ks++) {
            bf16x8 bhi[2], blo[2];
            #pragma unroll
            for (int ntl = 0; ntl < 2; ntl++) {
                const unsigned short* fb = &BswAll[((size_t)(ks * 16 + nt0 + ntl) * 64 + lane) * 16];
                bhi[ntl] = *(const bf16x8*)&fb[0];
                blo[ntl] = *(const bf16x8*)&fb[8];
            }
            #pragma unroll
            for (int mt = 0; mt < 4; mt++) {
                int ao = (mt * 16 + ln15) * XP + ks * 32 + q * 8;
                bf16x8 ahi = *(const bf16x8*)&fH[ao];
                bf16x8 alo = *(const bf16x8*)&fL[ao];
                #pragma unroll
                for (int ntl = 0; ntl < 2; ntl++) {
                    acc[mt][ntl] = __builtin_amdgcn_mfma_f32_16x16x32_bf16(ahi, bhi[ntl], acc[mt][ntl], 0, 0, 0);
                    acc[mt][ntl] = __builtin_amdgcn_mfma_f32_16x16x32_bf16(alo, bhi[ntl], acc[mt][ntl], 0, 0, 0);
                    acc[mt][ntl] = __builtin_amdgcn_mfma_f32_16x16x32_bf16(ahi, blo[ntl], acc[mt][ntl], 0, 0, 0);
                }
            }
        }
        #pragma unroll
        for (int ntl = 0; ntl < 2; ntl++) {
            int c = (nt0 + ntl) * 16 + ln15;
            float bv = inb[c];
            #pragma unroll
            for (int mt = 0; mt < 4; mt++) {
                #pragma unroll
                for (int r = 0; r < 4; r++) {
                    int m = mt * 16 + q * 4 + r;
                    float v = (acc[mt][ntl][r] + bv) * (vmS[m] > 0.5f ? 1.f : 0.f);
                    unsigned short hi = f2bf(v);
                    xH[m * XP + c] = hi;
                    xL[m * XP + c] = f2bf(v - bf2f(hi));
                }
            }
        }
    }
    __syncthreads();

    // ---- 3 GAT layers, x resident in LDS ----
    for (int l = 0; l < 3; l++) {
        const unsigned short* BswL = BswAll + (size_t)(1 + l) * 16384 * 16;
        const float* attSl = attSg + (size_t)l * 256;
        const float* attDl = attDg + (size_t)l * 256;
        const float* biasl = gbias + (size_t)l * 256;
        const float* lnsl  = glns + (size_t)l * 256;
        const float* lnbl  = glnb + (size_t)l * 256;
        const float* wES   = wESall + l * 12;

        // Phase B: h = x @ W  (A from xH/xL, pre-split; B from BswL, pre-split)
        f32x4 acc[4][2];
        #pragma unroll
        for (int mt = 0; mt < 4; mt++)
            #pragma unroll
            for (int ntl = 0; ntl < 2; ntl++) acc[mt][ntl] = (f32x4){0.f, 0.f, 0.f, 0.f};
        for (int ks = 0; ks < 8; ks++) {
            bf16x8 bhi[2], blo[2];
            #pragma unroll
            for (int ntl = 0; ntl < 2; ntl++) {
                const unsigned short* fb = &BswL[((size_t)(ks * 16 + nt0 + ntl) * 64 + lane) * 16];
                bhi[ntl] = *(const bf16x8*)&fb[0];
                blo[ntl] = *(const bf16x8*)&fb[8];
            }
            #pragma unroll
            for (int mt = 0; mt < 4; mt++) {
                int ao = (mt * 16 + ln15) * XP + ks * 32 + q * 8;
                bf16x8 ahi = *(const bf16x8*)&xH[ao];
                bf16x8 alo = *(const bf16x8*)&xL[ao];
                #pragma unroll
                for (int ntl = 0; ntl < 2; ntl++) {
                    acc[mt][ntl] = __builtin_amdgcn_mfma_f32_16x16x32_bf16(ahi, bhi[ntl], acc[mt][ntl], 0, 0, 0);
                    acc[mt][ntl] = __builtin_amdgcn_mfma_f32_16x16x32_bf16(alo, bhi[ntl], acc[mt][ntl], 0, 0, 0);
                    acc[mt][ntl] = __builtin_amdgcn_mfma_f32_16x16x32_bf16(ahi, blo[ntl], acc[mt][ntl], 0, 0, 0);
                }
            }
        }

        // Phase C: h -> hT (bf16 hi/lo, c-major) + per-wave a_src/a_dst partials.
        // This wave's 32 channels all belong to head w>>1.
        {
            float pSrc[4][4], pDst[4][4];
            #pragma unroll
            for (int mt = 0; mt < 4; mt++)
                #pragma unroll
                for (int r = 0; r < 4; r++) { pSrc[mt][r] = 0.f; pDst[mt][r] = 0.f; }
            #pragma unroll
            for (int ntl = 0; ntl < 2; ntl++) {
                int c = (nt0 + ntl) * 16 + ln15;
                float aS = attSl[c], aD = attDl[c];
                #pragma unroll
                for (int mt = 0; mt < 4; mt++) {
                    #pragma unroll
                    for (int r = 0; r < 4; r++) {
                        float v = acc[mt][ntl][r];
                        pSrc[mt][r] = fmaf(v, aS, pSrc[mt][r]);
                        pDst[mt][r] = fmaf(v, aD, pDst[mt][r]);
                        unsigned short hi = f2bf(v);
                        unsigned short lo = f2bf(v - bf2f(hi));
                        int s = mt * 16 + q * 4 + r;
                        hT[c * 136 + s] = hi;
                        hT[c * 136 + 64 + s] = lo;
                    }
                }
            }
            #pragma unroll
            for (int off = 1; off < 16; off <<= 1) {
                #pragma unroll
                for (int mt = 0; mt < 4; mt++)
                    #pragma unroll
                    for (int r = 0; r < 4; r++) {
                        pSrc[mt][r] += __shfl_xor(pSrc[mt][r], off);
                        pDst[mt][r] += __shfl_xor(pDst[mt][r], off);
                    }
            }
            if (ln15 == 0) {
                #pragma unroll
                for (int mt = 0; mt < 4; mt++)
                    #pragma unroll
                    for (int r = 0; r < 4; r++) {
                        int m = mt * 16 + q * 4 + r;
                        asrcS[w][m] = pSrc[mt][r];
                        adstS[w][m] = pDst[mt][r];
                    }
            }
        }
        __syncthreads();

        // Phase E: logits (A-frag layout), softmax, alpha hi/lo frags, P.H MFMA.
        f32x4 macc[2][4];
        #pragma unroll
        for (int t = 0; t < 2; t++)
            #pragma unroll
            for (int ct = 0; ct < 4; ct++) macc[t][ct] = (f32x4){0.f, 0.f, 0.f, 0.f};
        {
            float pxd[2], pyd[2], adstv[2], lp0[2], lp1[2], lp2[2];
            int dcur[2];
            bool vdv[2];
            #pragma unroll
            for (int t = 0; t < 2; t++) {
                int d = base_d + t * 16 + ln15;
                dcur[t] = d;
                pxd[t] = pxS[d]; pyd[t] = pyS[d];
                vdv[t] = vmS[d] > 0.5f;
                adstv[t] = adstS[2 * head][d] + adstS[2 * head + 1][d];
                lp0[t] = loopS[d * 3 + 0];
                lp1[t] = loopS[d * 3 + 1];
                lp2[t] = loopS[d * 3 + 2];
            }
            float we0 = wES[head], we1 = wES[4 + head], we2 = wES[8 + head];

            float lg[2][16];
            #pragma unroll
            for (int ks = 0; ks < 2; ks++) {
                int s0 = ks * 32 + q * 8;
                F8 PX, PY, VM, AS, A1;
                PX.v2[0] = *(const float4*)&pxS[s0]; PX.v2[1] = *(const float4*)&pxS[s0 + 4];
                PY.v2[0] = *(const float4*)&pyS[s0]; PY.v2[1] = *(const float4*)&pyS[s0 + 4];
                VM.v2[0] = *(const float4*)&vmS[s0]; VM.v2[1] = *(const float4*)&vmS[s0 + 4];
                AS.v2[0] = *(const float4*)&asrcS[2 * head][s0];
                AS.v2[1] = *(const float4*)&asrcS[2 * head][s0 + 4];
                A1.v2[0] = *(const float4*)&asrcS[2 * head + 1][s0];
                A1.v2[1] = *(const float4*)&asrcS[2 * head + 1][s0 + 4];
                #pragma unroll
                for (int j = 0; j < 8; j++) {
                    int s = s0 + j;
                    float vsf = VM.f[j];
                    float asv = AS.f[j] + A1.f[j];
                    #pragma unroll
                    for (int t = 0; t < 2; t++) {
                        float rx = pxd[t] - PX.f[j], ry = pyd[t] - PY.f[j];
                        float dist = sqrtf(fmaxf(rx * rx + ry * ry, 1e-12f));
                        bool self = (s == dcur[t]);
                        bool adj = vdv[t] && (vsf > 0.5f) && (dist < 0.3f) && !self;
                        float e0 = adj ? dist : (self ? lp0[t] : 0.f);
                        float e1 = adj ? rx   : (self ? lp1[t] : 0.f);
                        float e2 = adj ? ry   : (self ? lp2[t] : 0.f);
                        bool fa = adj || (self && vdv[t]);
                        float lv = asv + adstv[t] + e0 * we0 + e1 * we1 + e2 * we2;
                        lv = lv >= 0.f ? lv : 0.2f * lv;
                        lg[t][ks * 8 + j] = fa ? lv : -1e9f;
                    }
                }
            }

            // softmax over s (in-lane 16 + xor16/xor32 over q) + alpha frags
            bf16x8 ah[2][2], al[2][2];
            #pragma unroll
            for (int t = 0; t < 2; t++) {
                float mx = lg[t][0];
                #pragma unroll
                for (int j = 1; j < 16; j++) mx = fmaxf(mx, lg[t][j]);
                mx = fmaxf(mx, __shfl_xor(mx, 16));
                mx = fmaxf(mx, __shfl_xor(mx, 32));
                float ee[16], sm = 0.f;
                #pragma unroll
                for (int j = 0; j < 16; j++) { ee[j] = __expf(lg[t][j] - mx); sm += ee[j]; }
                sm += __shfl_xor(sm, 16);
                sm += __shfl_xor(sm, 32);
                float inv = 1.f / sm;
                #pragma unroll
                for (int ks2 = 0; ks2 < 2; ks2++) {
                    union { bf16x8 v; unsigned short u[8]; } H, L;
                    #pragma unroll
                    for (int j = 0; j < 8; j++) {
                        float a = ee[ks2 * 8 + j] * inv;
                        unsigned short hi = f2bf(a);
                        H.u[j] = hi;
                        L.u[j] = f2bf(a - bf2f(hi));
                    }
                    ah[t][ks2] = H.v; al[t][ks2] = L.v;
                }
            }

            // P.H MFMA: msg[d][c] for d in base_d..+32, c in head*64..+64
            #pragma unroll
            for (int t = 0; t < 2; t++) {
                #pragma unroll
                for (int ks2 = 0; ks2 < 2; ks2++) {
                    #pragma unroll
                    for (int ct = 0; ct < 4; ct++) {
                        const unsigned short* hb =
                            &hT[(size_t)(head * 64 + ct * 16 + ln15) * 136 + ks2 * 32 + q * 8];
                        bf16x8 bhi = *(const bf16x8*)&hb[0];
                        bf16x8 blo = *(const bf16x8*)&hb[64];
                        macc[t][ct] = __builtin_amdgcn_mfma_f32_16x16x32_bf16(ah[t][ks2], bhi, macc[t][ct], 0, 0, 0);
                        macc[t][ct] = __builtin_amdgcn_mfma_f32_16x16x32_bf16(al[t][ks2], bhi, macc[t][ct], 0, 0, 0);
                        macc[t][ct] = __builtin_amdgcn_mfma_f32_16x16x32_bf16(ah[t][ks2], blo, macc[t][ct], 0, 0, 0);
                    }
                }
            }
        }

        // Phase F: LN(msg + bias + x_old) + relu, write back to xH/xL.
        {
            float bsv[4], scv[4], bbv[4];
            #pragma unroll
            for (int ct = 0; ct < 4; ct++) {
                int c = head * 64 + ct * 16 + ln15;
                bsv[ct] = biasl[c];
                scv[ct] = lnsl[c];
                bbv[ct] = lnbl[c];
            }
            float xo[2][4][4];
            #pragma unroll
            for (int t = 0; t < 2; t++)
                #pragma unroll
                for (int r = 0; r < 4; r++) {
                    int d = base_d + t * 16 + q * 4 + r;
                    #pragma unroll
                    for (int ct = 0; ct < 4; ct++) {
                        int o = d * XP + head * 64 + ct * 16 + ln15;
                        xo[t][ct][r] = bf2f(xH[o]) + bf2f(xL[o]);
                    }
                }
            float ps[8], ps2[8];
            #pragma unroll
            for (int t = 0; t < 2; t++)
                #pragma unroll
                for (int r = 0; r < 4; r++) {
                    float s = 0.f, s2 = 0.f;
                    #pragma unroll
                    for (int ct = 0; ct < 4; ct++) {
                        float v = macc[t][ct][r] + xo[t][ct][r] + bsv[ct];
                        s += v; s2 += v * v;
                    }
                    ps[t * 4 + r] = s; ps2[t * 4 + r] = s2;
                }
            #pragma unroll
            for (int off = 1; off < 16; off <<= 1) {
                #pragma unroll
                for (int i = 0; i < 8; i++) {
                    ps[i]  += __shfl_xor(ps[i], off);
                    ps2[i] += __shfl_xor(ps2[i], off);
                }
            }
            if (ln15 == 0) {
                #pragma unroll
                for (int t = 0; t < 2; t++)
                    #pragma unroll
                    for (int r = 0; r < 4; r++) {
                        int d = base_d + t * 16 + q * 4 + r;
                        sumsS[d][head * 2 + 0] = ps[t * 4 + r];
                        sumsS[d][head * 2 + 1] = ps2[t * 4 + r];
                    }
            }
            __syncthreads();
            if (tid < 64) {
                float S  = sumsS[tid][0] + sumsS[tid][2] + sumsS[tid][4] + sumsS[tid][6];
                float S2 = sumsS[tid][1] + sumsS[tid][3] + sumsS[tid][5] + sumsS[tid][7];
                float mu = S * (1.f / 256.f);
                float var = S2 * (1.f / 256.f) - mu * mu;
                mrsS[tid][0] = mu;
                mrsS[tid][1] = rsqrtf(var + 1e-5f);
            }
            __syncthreads();
            #pragma unroll
            for (int t = 0; t < 2; t++)
                #pragma unroll
                for (int r = 0; r < 4; r++) {
                    int d = base_d + t * 16 + q * 4 + r;
                    float mu = mrsS[d][0], rs = mrsS[d][1];
                    #pragma unroll
                    for (int ct = 0; ct < 4; ct++) {
                        float v = (macc[t][ct][r] + xo[t][ct][r] + bsv[ct] - mu) * rs * scv[ct] + bbv[ct];
                        v = fmaxf(v, 0.f);
                        unsigned short hi = f2bf(v);
                        int o = d * XP + head * 64 + ct * 16 + ln15;
                        xH[o] = hi;
                        xL[o] = f2bf(v - bf2f(hi));
                    }
                }
        }
        __syncthreads();   // x ready for next layer / frame mean
    }

    // ---- masked frame mean -> framebuf ----
    if (tid < 256) {
        float s = 0.f;
        for (int m = 0; m < 64; m++) {
            float xv = bf2f(xH[m * XP + tid]) + bf2f(xL[m * XP + tid]);
            s += xv * (vmS[m] > 0.5f ? 1.f : 0.f);
        }
        framebuf[(size_t)bt * 256 + tid] = s / nvS;
    }
}

// ---------------------------------------------------------------------------
// temp proj from precomputed frame means, 4 tokens per block
__global__ __launch_bounds__(256) void k_temp4(const float* __restrict__ framebuf,
                                               const float* __restrict__ tW,
                                               const float* __restrict__ tb,
                                               const float* __restrict__ pe,
                                               float* __restrict__ ybuf) {
    int b4 = blockIdx.x;   // 0..511
    int tid = threadIdx.x;
    __shared__ float frS[4][256];
    #pragma unroll
    for (int t = 0; t < 4; t++) frS[t][tid] = framebuf[(size_t)(b4 * 4 + t) * 256 + tid];
    __syncthreads();
    float acc[4];
    #pragma unroll
    for (int t = 0; t < 4; t++) acc[t] = tb[tid] + pe[((b4 * 4 + t) & 31) * 256 + tid];
    const float* wrow = tW + (size_t)tid * 256;
    for (int g = 0; g < 256; g += 4) {
        float4 wv = *(const float4*)&wrow[g];
        #pragma unroll
        for (int t = 0; t < 4; t++) acc[t] += dot4(*(const float4*)&frS[t][g], wv);
    }
    #pragma unroll
    for (int t = 0; t < 4; t++) ybuf[(size_t)(b4 * 4 + t) * 256 + tid] = acc[t];
}

// ---------------------------------------------------------------------------
// LN1 + qkv, 4 tokens per block; wave-per-token LN.
__global__ __launch_bounds__(256) void k_ln_qkv4(const float* __restrict__ ybuf,
                                                 const float* __restrict__ ln_s,
                                                 const float* __restrict__ ln_b,
                                                 const float* __restrict__ qW,
                                                 const float* __restrict__ qb,
                                                 float* __restrict__ qkvbuf) {
    int b4 = blockIdx.x, tid = threadIdx.x;
    int lane = tid & 63, wv = tid >> 6;
    __shared__ float zS[4][256];
    {
        int bt = b4 * 4 + wv;
        float4 yv = *(const float4*)&ybuf[(size_t)bt * 256 + lane * 4];
        float s = yv.x + yv.y + yv.z + yv.w;
        float s2 = yv.x * yv.x + yv.y * yv.y + yv.z * yv.z + yv.w * yv.w;
        #pragma unroll
        for (int off = 1; off < 64; off <<= 1) { s += __shfl_xor(s, off); s2 += __shfl_xor(s2, off); }
        float mu = s * (1.f / 256.f);
        float var = s2 * (1.f / 256.f) - mu * mu;
        float rstd = rsqrtf(var + 1e-5f);
        float4 ls = *(const float4*)&ln_s[lane * 4];
        float4 lb = *(const float4*)&ln_b[lane * 4];
        float4 z;
        z.x = (yv.x - mu) * rstd * ls.x + lb.x;
        z.y = (yv.y - mu) * rstd * ls.y + lb.y;
        z.z = (yv.z - mu) * rstd * ls.z + lb.z;
        z.w = (yv.w - mu) * rstd * ls.w + lb.w;
        *(float4*)&zS[wv][lane * 4] = z;
    }
    __syncthreads();
    for (int r = 0; r < 3; r++) {
        int j = r * 256 + tid;
        float acc[4];
        float bv = qb[j];
        #pragma unroll
        for (int t = 0; t < 4; t++) acc[t] = bv;
        const float* wrow = qW + (size_t)j * 256;
        for (int i = 0; i < 256; i += 4) {
            float4 wv4 = *(const float4*)&wrow[i];
            #pragma unroll
            for (int t = 0; t < 4; t++) acc[t] += dot4(*(const float4*)&zS[t][i], wv4);
        }
        #pragma unroll
        for (int t = 0; t < 4; t++) qkvbuf[(size_t)(b4 * 4 + t) * 768 + j] = acc[t];
    }
}

// ---------------------------------------------------------------------------
__global__ __launch_bounds__(64) void k_attn(const float* __restrict__ qkvbuf,
                                             float* __restrict__ obuf) {
    int blk = blockIdx.x;
    int b = blk >> 3, h = blk & 7;
    int tid = threadIdx.x;
    __shared__ float Ks[32 * 32], Vs[32 * 32];
    for (int idx = tid; idx < 1024; idx += 64) {
        int tk = idx >> 5, c = idx & 31;
        size_t qbase = ((size_t)(b * 32 + tk)) * 768 + h * 32 + c;
        Ks[idx] = qkvbuf[qbase + 256];
        Vs[idx] = qkvbuf[qbase + 512];
    }
    __syncthreads();
    if (tid < 32) {
        int tq = tid;
        float qv[32];
        size_t qb0 = ((size_t)(b * 32 + tq)) * 768 + h * 32;
        #pragma unroll
        for (int c = 0; c < 32; c++) qv[c] = qkvbuf[qb0 + c];
        float scr[32];
        float mx = -1e30f;
        #pragma unroll
        for (int tk = 0; tk < 32; tk++) {
            float dd = 0.f;
            #pragma unroll
            for (int c = 0; c < 32; c++) dd = fmaf(qv[c], Ks[tk * 32 + c], dd);
            dd *= 0.17677669529663687f;
            scr[tk] = dd;
            mx = fmaxf(mx, dd);
        }
        float sm = 0.f;
        #pragma unroll
        for (int tk = 0; tk < 32; tk++) { scr[tk] = __expf(scr[tk] - mx); sm += scr[tk]; }
        float inv = 1.f / sm;
        float o[32];
        #pragma unroll
        for (int c = 0; c < 32; c++) o[c] = 0.f;
        #pragma unroll
        for (int tk = 0; tk < 32; tk++) {
            float a = scr[tk] * inv;
            #pragma unroll
            for (int c = 0; c < 32; c++) o[c] = fmaf(a, Vs[tk * 32 + c], o[c]);
        }
        size_t ob = ((size_t)(b * 32 + tq)) * 256 + h * 32;
        #pragma unroll
        for (int c = 0; c < 32; c++) obuf[ob + c] = o[c];
    }
}

// ---------------------------------------------------------------------------
__global__ __launch_bounds__(256) void k_attn_out4(const float* __restrict__ obuf,
                                                   const float* __restrict__ W,
                                                   const float* __restrict__ bvec,
                                                   float* __restrict__ ybuf) {
    int b4 = blockIdx.x, tid = threadIdx.x;
    int lane = tid & 63, wv = tid >> 6;
    __shared__ float oS[4][256];
    *(float4*)&oS[wv][lane * 4] = *(const float4*)&obuf[(size_t)(b4 * 4 + wv) * 256 + lane * 4];
    __syncthreads();
    float acc[4];
    float bv = bvec[tid];
    #pragma unroll
    for (int t = 0; t < 4; t++) acc[t] = bv;
    const float* wrow = W + (size_t)tid * 256;
    for (int i = 0; i < 256; i += 4) {
        float4 wv4 = *(const float4*)&wrow[i];
        #pragma unroll
        for (int t = 0; t < 4; t++) acc[t] += dot4(*(const float4*)&oS[t][i], wv4);
    }
    #pragma unroll
    for (int t = 0; t < 4; t++) ybuf[(size_t)(b4 * 4 + t) * 256 + tid] += acc[t];
}

// ---------------------------------------------------------------------------
__global__ __launch_bounds__(256) void k_ff4(float* __restrict__ ybuf,
                                             const float* __restrict__ ln_s,
                                             const float* __restrict__ ln_b,
                                             const float* __restrict__ W1,
                                             const float* __restrict__ b1,
                                             const float* __restrict__ W2,
                                             const float* __restrict__ b2) {
    int b4 = blockIdx.x, tid = threadIdx.x;
    int lane = tid & 63, wv = tid >> 6;
    __shared__ float zS[4][256];
    __shared__ float fS[4][512];
    {
        int bt = b4 * 4 + wv;
        float4 yv = *(const float4*)&ybuf[(size_t)bt * 256 + lane * 4];
        float s = yv.x + yv.y + yv.z + yv.w;
        float s2 = yv.x * yv.x + yv.y * yv.y + yv.z * yv.z + yv.w * yv.w;
        #pragma unroll
        for (int off = 1; off < 64; off <<= 1) { s += __shfl_xor(s, off); s2 += __shfl_xor(s2, off); }
        float mu = s * (1.f / 256.f);
        float var = s2 * (1.f / 256.f) - mu * mu;
        float rstd = rsqrtf(var + 1e-5f);
        float4 ls = *(const float4*)&ln_s[lane * 4];
        float4 lb = *(const float4*)&ln_b[lane * 4];
        float4 z;
        z.x = (yv.x - mu) * rstd * ls.x + lb.x;
        z.y = (yv.y - mu) * rstd * ls.y + lb.y;
        z.z = (yv.z - mu) * rstd * ls.z + lb.z;
        z.w = (yv.w - mu) * rstd * ls.w + lb.w;
        *(float4*)&zS[wv][lane * 4] = z;
    }
    __syncthreads();
    for (int r = 0; r < 2; r++) {
        int j = r * 256 + tid;
        float acc[4];
        float bv = b1[j];
        #pragma unroll
        for (int t = 0; t < 4; t++) acc[t] = bv;
        const float* wrow = W1 + (size_t)j * 256;
        for (int i = 0; i < 256; i += 4) {
            float4 wv4 = *(const float4*)&wrow[i];
            #pragma unroll
            for (int t = 0; t < 4; t++) acc[t] += dot4(*(const float4*)&zS[t][i], wv4);
        }
        #pragma unroll
        for (int t = 0; t < 4; t++) fS[t][j] = fmaxf(acc[t], 0.f);
    }
    __syncthreads();
    float acc[4];
    float bv = b2[tid];
    #pragma unroll
    for (int t = 0; t < 4; t++) acc[t] = bv;
    const float* wrow = W2 + (size_t)tid * 512;
    for (int jj = 0; jj < 512; jj += 4) {
        float4 wv4 = *(const float4*)&wrow[jj];
        #pragma unroll
        for (int t = 0; t < 4; t++) acc[t] += dot4(*(const float4*)&fS[t][jj], wv4);
    }
    #pragma unroll
    for (int t = 0; t < 4; t++) {
        size_t idx = (size_t)(b4 * 4 + t) * 256 + tid;
        ybuf[idx] = ybuf[idx] + acc[t];
    }
}

// ---------------------------------------------------------------------------
__global__ __launch_bounds__(256) void k_pool_out(const float* __restrict__ ybuf,
                                                  const float* __restrict__ pW,
                                                  const float* __restrict__ pb,
                                                  const float* __restrict__ oW,
                                                  const float* __restrict__ ob,
                                                  const float* __restrict__ lns,
                                                  const float* __restrict__ lnb,
                                                  float* __restrict__ dout) {
    int b = blockIdx.x, tid = threadIdx.x;
    __shared__ float redP[256];
    __shared__ float wS[32];
    __shared__ float pS[256];
    __shared__ float red[8];
    int tq = tid >> 3, part = tid & 7;
    float partial = 0.f;
    {
        const float* yrow = ybuf + ((size_t)(b * 32 + tq)) * 256 + part * 32;
        const float* pwp = pW + part * 32;
        #pragma unroll
        for (int j = 0; j < 32; j += 4) {
            float4 yv = *(const float4*)&yrow[j];
            float4 wv = *(const float4*)&pwp[j];
            partial += dot4(yv, wv);
        }
    }
    redP[tid] = partial;
    __syncthreads();
    if (tid < 32) {
        float s = pb[0];
        for (int p = 0; p < 8; p++) s += redP[tid * 8 + p];
        float mx = s;
        #pragma unroll
        for (int off = 16; off; off >>= 1) mx = fmaxf(mx, __shfl_xor(mx, off));
        float e = __expf(s - mx);
        float sm = e;
        #pragma unroll
        for (int off = 16; off; off >>= 1) sm += __shfl_xor(sm, off);
        wS[tid] = e / sm;
    }
    __syncthreads();
    float p = 0.f;
    for (int t = 0; t < 32; t++) p += ybuf[((size_t)(b * 32 + t)) * 256 + tid] * wS[t];
    pS[tid] = p;
    __syncthreads();
    float accs[2];
    for (int r = 0; r < 2; r++) {
        int j = r * 256 + tid;
        float acc = ob[j];
        const float* wrow = oW + (size_t)j * 256;
        for (int g = 0; g < 256; g += 4) {
            float4 pv = *(const float4*)&pS[g];
            float4 wv = *(const float4*)&wrow[g];
            acc += dot4(pv, wv);
        }
        accs[r] = acc;
    }
    float s = accs[0] + accs[1];
    float s2 = accs[0] * accs[0] + accs[1] * accs[1];
    #pragma unroll
    for (int off = 32; off; off >>= 1) {
        s += __shfl_xor(s, off);
        s2 += __shfl_xor(s2, off);
    }
    int wid = threadIdx.x >> 6;
    int lane = threadIdx.x & 63;
    if (lane == 0) { red[wid] = s; red[4 + wid] = s2; }
    __syncthreads();
    s = red[0] + red[1] + red[2] + red[3];
    s2 = red[4] + red[5] + red[6] + red[7];
    float mu = s * (1.f / 512.f);
    float var = s2 * (1.f / 512.f) - mu * mu;
    float rstd = rsqrtf(var + 1e-5f);
    dout[b * 512 + tid]       = fmaxf((accs[0] - mu) * rstd * lns[tid] + lnb[tid], 0.f);
    dout[b * 512 + tid + 256] = fmaxf((accs[1] - mu) * rstd * lns[tid + 256] + lnb[tid + 256], 0.f);
}

// ---------------------------------------------------------------------------
extern "C" void kernel_launch(void* const* d_in, const int* in_sizes, int n_in,
                              void* d_out, int out_size, void* d_ws, size_t ws_size,
                              hipStream_t stream) {
    const float* drone_feats = (const float*)d_in[0];
    const float* boxes       = (const float*)d_in[1];
    const float* drone_mask  = (const float*)d_in[2];
    const float* in_proj_W   = (const float*)d_in[3];
    const float* in_proj_b   = (const float*)d_in[4];
    const float* gat_lin_W   = (const float*)d_in[5];
    const float* gat_edge_W  = (const float*)d_in[6];
    const float* gat_att_src = (const float*)d_in[7];
    const float* gat_att_dst = (const float*)d_in[8];
    const float* gat_att_edge= (const float*)d_in[9];
    const float* gat_bias    = (const float*)d_in[10];
    const float* gat_ln_s    = (const float*)d_in[11];
    const float* gat_ln_b    = (const float*)d_in[12];
    const float* temp_W      = (const float*)d_in[13];
    const float* temp_b      = (const float*)d_in[14];
    const float* pos_emb     = (const float*)d_in[15];
    const float* qkv_W       = (const float*)d_in[16];
    const float* qkv_b       = (const float*)d_in[17];
    const float* attn_out_W  = (const float*)d_in[18];
    const float* attn_out_b  = (const float*)d_in[19];
    const float* ln1_s       = (const float*)d_in[20];
    const float* ln1_b       = (const float*)d_in[21];
    const float* ln2_s       = (const float*)d_in[22];
    const float* ln2_b       = (const float*)d_in[23];
    const float* ff1_W       = (const float*)d_in[24];
    const float* ff1_b       = (const float*)d_in[25];
    const float* ff2_W       = (const float*)d_in[26];
    const float* ff2_b       = (const float*)d_in[27];
    const float* pool_W      = (const float*)d_in[28];
    const float* pool_b      = (const float*)d_in[29];
    const float* out_W       = (const float*)d_in[30];
    const float* out_b       = (const float*)d_in[31];
    const float* out_ln_s    = (const float*)d_in[32];
    const float* out_ln_b    = (const float*)d_in[33];
    float* out = (float*)d_out;

    float* ws = (float*)d_ws;
    unsigned short* Bsw = (unsigned short*)ws;           // 4*16384*16 ushorts = 2 MB
    size_t off = (size_t)(4 * 16384 * 16) / 2;           // in floats
    float* framebuf = ws + off; off += (size_t)BT * 256;
    float* ybuf   = ws + off; off += (size_t)BT * 256;
    float* qkvbuf = ws + off; off += (size_t)BT * 768;
    float* obuf   = ws + off; off += (size_t)BT * 256;

    k_prep<<<dim3(256), dim3(256), 0, stream>>>(in_proj_W, gat_lin_W, Bsw);
    k_gnn<<<dim3(BT), dim3(512), 0, stream>>>(drone_feats, boxes, drone_mask, Bsw,
        in_proj_b, gat_edge_W, gat_att_src, gat_att_dst, gat_att_edge,
        gat_bias, gat_ln_s, gat_ln_b, framebuf);
    k_temp4<<<dim3(BT / 4), dim3(256), 0, stream>>>(framebuf, temp_W, temp_b, pos_emb, ybuf);
    for (int l = 0; l < 2; l++) {
        k_ln_qkv4<<<dim3(BT / 4), dim3(256), 0, stream>>>(ybuf, ln1_s + l * 256, ln1_b + l * 256,
            qkv_W + (size_t)l * 768 * 256, qkv_b + l * 768, qkvbuf);
        k_attn<<<dim3(512), dim3(64), 0, stream>>>(qkvbuf, obuf);
        k_attn_out4<<<dim3(BT / 4), dim3(256), 0, stream>>>(obuf,
            attn_out_W + (size_t)l * 65536, attn_out_b + l * 256, ybuf);
        k_ff4<<<dim3(BT / 4), dim3(256), 0, stream>>>(ybuf, ln2_s + l * 256, ln2_b + l * 256,
            ff1_W + (size_t)l * 131072, ff1_b + l * 512,
            ff2_W + (size_t)l * 131072, ff2_b + l * 256);
    }
    k_pool_out<<<dim3(64), dim3(256), 0, stream>>>(ybuf, pool_W, pool_b, out_W, out_b,
                                                   out_ln_s, out_ln_b, out);
}